// Round 14
// baseline (1357.158 us; speedup 1.0000x reference)
//
#include <hip/hip_runtime.h>
#include <hip/hip_bf16.h>

// Problem constants
#define BB 64
#define TT 2048
#define II 128
#define HH 256
#define OO 128

typedef float f32x4v __attribute__((ext_vector_type(4)));
typedef short bf16x8 __attribute__((ext_vector_type(8)));

__device__ __forceinline__ unsigned short f2bf(float f) {
    union { __hip_bfloat16 h; unsigned short u; } cv;
    cv.h = __float2bfloat16(f);   // RNE
    return cv.u;
}
__device__ __forceinline__ float tanh_fast(float x) {
    // tanh(x) = 1 - 2/(e^{2x}+1);  e^{2x} = 2^{x*2*log2(e)}
    float y = x * 2.88539008177793f;
    float e;
    asm("v_exp_f32 %0, %1" : "=v"(e) : "v"(y));
    return 1.0f - 2.0f * __builtin_amdgcn_rcpf(e + 1.0f);
}

// within-32 permutation: storage position p holds true column
//   T(p)   = (p & ~31) + 16*(p&1) + ((p&31)>>1)
//   pos(c) = (c & ~31) + 2*(c&15) + ((c&31)>>4)     (inverse; verified)

#define MM(a, b, c) c = __builtin_amdgcn_mfma_f32_16x16x32_bf16(a, b, c, 0, 0, 0);

// ---------------------------------------------------------------------------
// Phase 1 (MFMA): xproj[m][pos] = (x*Wi^T)[m][T(pos)] + bi + bh
// M-tile 128 (R14: halves per-row staging cost vs 64). 256 thr / 4 waves;
// wave handles rows m0..m0+15 and m0+64..m0+79.
// ---------------------------------------------------------------------------
#define WIPAD 136   // ushorts per wiL row

__global__ __launch_bounds__(256) void gemm1_mfma(
    const float* __restrict__ x, const float* __restrict__ Wi,
    const float* __restrict__ bi, const float* __restrict__ bh,
    float* __restrict__ xproj)
{
    __shared__ __align__(16) unsigned short wiL[HH][WIPAD];   // 69.6 KB

    const int tid = threadIdx.x;
    const int wv = tid >> 6, lane = tid & 63;
    const int l15 = lane & 15, lg = lane >> 4;
    const int m0 = blockIdx.x * 128 + wv * 16;

    // stage Wi -> LDS bf16 (coalesced flat reads)
    for (int e = tid; e < HH * II; e += 256)
        wiL[e >> 7][e & 127] = f2bf(Wi[e]);
    __syncthreads();

    // A-frags: rows m0+l15 (a0..a3) and m0+64+l15 (a4..a7), fp32 -> bf16
    const float* xr0 = x + (size_t)(m0 + l15) * II + lg * 8;
    const float* xr1 = x + (size_t)(m0 + 64 + l15) * II + lg * 8;
    bf16x8 a0, a1, a2, a3, a4, a5, a6, a7;
#define LOADA1(ptr, q, dst) { \
        float4 u0 = *(const float4*)((ptr) + (q) * 32); \
        float4 u1 = *(const float4*)((ptr) + (q) * 32 + 4); \
        dst[0] = (short)f2bf(u0.x); dst[1] = (short)f2bf(u0.y); \
        dst[2] = (short)f2bf(u0.z); dst[3] = (short)f2bf(u0.w); \
        dst[4] = (short)f2bf(u1.x); dst[5] = (short)f2bf(u1.y); \
        dst[6] = (short)f2bf(u1.z); dst[7] = (short)f2bf(u1.w); }
    LOADA1(xr0, 0, a0) LOADA1(xr0, 1, a1) LOADA1(xr0, 2, a2) LOADA1(xr0, 3, a3)
    LOADA1(xr1, 0, a4) LOADA1(xr1, 1, a5) LOADA1(xr1, 2, a6) LOADA1(xr1, 3, a7)

    // 16 N-tiles x 4 K-steps x 2 M-subtiles; permuted scatter stores
#pragma unroll
    for (int nt = 0; nt < 16; ++nt) {
        const int c = nt * 16 + l15;            // true column
        const float bv = bi[c] + bh[c];
        f32x4v acc0 = {bv, bv, bv, bv};
        f32x4v acc1 = {bv, bv, bv, bv};
        const unsigned short* wrow = &wiL[nt * 16 + l15][lg * 8];
        bf16x8 b0 = *(const bf16x8*)(wrow + 0);
        bf16x8 b1 = *(const bf16x8*)(wrow + 32);
        bf16x8 b2 = *(const bf16x8*)(wrow + 64);
        bf16x8 b3 = *(const bf16x8*)(wrow + 96);
        MM(a0, b0, acc0) MM(a1, b1, acc0) MM(a2, b2, acc0) MM(a3, b3, acc0)
        MM(a4, b0, acc1) MM(a5, b1, acc1) MM(a6, b2, acc1) MM(a7, b3, acc1)

        const int pos = (c & ~31) + 2 * (c & 15) + ((c & 31) >> 4);
#pragma unroll
        for (int r = 0; r < 4; ++r) {
            xproj[(size_t)(m0 + lg * 4 + r) * HH + pos] = acc0[r];
            xproj[(size_t)(m0 + 64 + lg * 4 + r) * HH + pos] = acc1[r];
        }
    }
}

// ---------------------------------------------------------------------------
// Phase 3 (MFMA): out = hs*Wo^T + bo. hs bf16 pos-space; Wo staged to LDS
// pre-permuted. M-tile 128 (B-frag LDS reads amortized over 2 M-subtiles).
// ---------------------------------------------------------------------------
#define WOPAD 264   // ushorts per woL row

__global__ __launch_bounds__(256) void gemm3_mfma(
    const unsigned short* __restrict__ hs, const float* __restrict__ Wo,
    const float* __restrict__ bo, float* __restrict__ out)
{
    __shared__ __align__(16) unsigned short woL[OO][WOPAD];   // 67.6 KB

    const int tid = threadIdx.x;
    const int wv = tid >> 6, lane = tid & 63;
    const int l15 = lane & 15, lg = lane >> 4;
    const int m0 = blockIdx.x * 128 + wv * 16;

    // stage Wo -> LDS bf16, permuted into pos space
    for (int e = tid; e < OO * HH; e += 256) {
        const int o = e >> 8, c = e & 255;
        const int pos = (c & ~31) + 2 * (c & 15) + ((c & 31) >> 4);
        woL[o][pos] = f2bf(Wo[e]);
    }
    __syncthreads();

    // A-frags: rows m0+l15 and m0+64+l15 (pos-space), direct b128 global
    const unsigned short* hr0 = hs + (size_t)(m0 + l15) * HH + lg * 8;
    const unsigned short* hr1 = hs + (size_t)(m0 + 64 + l15) * HH + lg * 8;
    bf16x8 a0 = *(const bf16x8*)(hr0 + 0);
    bf16x8 a1 = *(const bf16x8*)(hr0 + 32);
    bf16x8 a2 = *(const bf16x8*)(hr0 + 64);
    bf16x8 a3 = *(const bf16x8*)(hr0 + 96);
    bf16x8 a4 = *(const bf16x8*)(hr0 + 128);
    bf16x8 a5 = *(const bf16x8*)(hr0 + 160);
    bf16x8 a6 = *(const bf16x8*)(hr0 + 192);
    bf16x8 a7 = *(const bf16x8*)(hr0 + 224);
    bf16x8 e0 = *(const bf16x8*)(hr1 + 0);
    bf16x8 e1 = *(const bf16x8*)(hr1 + 32);
    bf16x8 e2 = *(const bf16x8*)(hr1 + 64);
    bf16x8 e3 = *(const bf16x8*)(hr1 + 96);
    bf16x8 e4 = *(const bf16x8*)(hr1 + 128);
    bf16x8 e5 = *(const bf16x8*)(hr1 + 160);
    bf16x8 e6 = *(const bf16x8*)(hr1 + 192);
    bf16x8 e7 = *(const bf16x8*)(hr1 + 224);

    // 8 N-tiles x 8 K-steps x 2 M-subtiles
#pragma unroll
    for (int nt = 0; nt < 8; ++nt) {
        const float bv = bo[nt * 16 + l15];
        f32x4v acc0 = {bv, bv, bv, bv};
        f32x4v acc1 = {bv, bv, bv, bv};
        const unsigned short* wrow = &woL[nt * 16 + l15][lg * 8];
        bf16x8 b0 = *(const bf16x8*)(wrow + 0);
        bf16x8 b1 = *(const bf16x8*)(wrow + 32);
        bf16x8 b2 = *(const bf16x8*)(wrow + 64);
        bf16x8 b3 = *(const bf16x8*)(wrow + 96);
        bf16x8 b4 = *(const bf16x8*)(wrow + 128);
        bf16x8 b5 = *(const bf16x8*)(wrow + 160);
        bf16x8 b6 = *(const bf16x8*)(wrow + 192);
        bf16x8 b7 = *(const bf16x8*)(wrow + 224);
        MM(a0, b0, acc0) MM(a1, b1, acc0) MM(a2, b2, acc0) MM(a3, b3, acc0)
        MM(a4, b4, acc0) MM(a5, b5, acc0) MM(a6, b6, acc0) MM(a7, b7, acc0)
        MM(e0, b0, acc1) MM(e1, b1, acc1) MM(e2, b2, acc1) MM(e3, b3, acc1)
        MM(e4, b4, acc1) MM(e5, b5, acc1) MM(e6, b6, acc1) MM(e7, b7, acc1)

#pragma unroll
        for (int r = 0; r < 4; ++r) {
            out[(size_t)(m0 + lg * 4 + r) * OO + nt * 16 + l15] = acc0[r];
            out[(size_t)(m0 + 64 + lg * 4 + r) * OO + nt * 16 + l15] = acc1[r];
        }
    }
}

// ---------------------------------------------------------------------------
// Recurrence: R13 VERBATIM + s_setprio(1) around the MFMA cluster (T5 test).
// ---------------------------------------------------------------------------
#define G 16
#define HPAD 264    // ushorts per h row (528B)

__global__ __launch_bounds__(512) __attribute__((amdgpu_waves_per_eu(2, 2)))
void rnn_recurrence_mfma(
    const float* __restrict__ xproj, const float* __restrict__ Wh,
    unsigned short* __restrict__ hs)
{
    __shared__ __align__(16) unsigned short hbl[2][G][HPAD];

    const int blk  = blockIdx.x;         // 0..3
    const int tid  = threadIdx.x;        // 0..511
    const int wave = tid >> 6;           // 0..7
    const int lane = tid & 63;
    const int l15  = lane & 15;
    const int lg   = lane >> 4;          // 0..3
    const int n0   = wave * 32;          // wave's 32-unit block

    // one-time B-frags (within-32 K-gather)
#define LOADB(nt, kt, dst) { \
        const float* wp = Wh + (size_t)(n0 + (nt)*16 + l15) * HH + (kt)*32 + lg*4; \
        dst[0] = (short)f2bf(wp[0]);  dst[1] = (short)f2bf(wp[16]); \
        dst[2] = (short)f2bf(wp[1]);  dst[3] = (short)f2bf(wp[17]); \
        dst[4] = (short)f2bf(wp[2]);  dst[5] = (short)f2bf(wp[18]); \
        dst[6] = (short)f2bf(wp[3]);  dst[7] = (short)f2bf(wp[19]); }

    bf16x8 B00, B01, B02, B03, B04, B05, B06, B07;
    bf16x8 B10, B11, B12, B13, B14, B15, B16, B17;
    LOADB(0, 0, B00) LOADB(0, 1, B01) LOADB(0, 2, B02) LOADB(0, 3, B03)
    LOADB(0, 4, B04) LOADB(0, 5, B05) LOADB(0, 6, B06) LOADB(0, 7, B07)
    LOADB(1, 0, B10) LOADB(1, 1, B11) LOADB(1, 2, B12) LOADB(1, 3, B13)
    LOADB(1, 4, B14) LOADB(1, 5, B15) LOADB(1, 6, B16) LOADB(1, 7, B17)

    // per-thread 4 batch rows (m = lg*4 + r), permuted col offset n0 + 2*l15
    const int mb = blk * G + lg * 4;
    const float* xq0 = xproj + (size_t)(mb + 0) * TT * HH + n0 + 2 * l15;
    const float* xq1 = xproj + (size_t)(mb + 1) * TT * HH + n0 + 2 * l15;
    const float* xq2 = xproj + (size_t)(mb + 2) * TT * HH + n0 + 2 * l15;
    const float* xq3 = xproj + (size_t)(mb + 3) * TT * HH + n0 + 2 * l15;
    unsigned short* hq0 = hs + (size_t)(mb + 0) * TT * HH + n0 + 2 * l15;
    unsigned short* hq1 = hs + (size_t)(mb + 1) * TT * HH + n0 + 2 * l15;
    unsigned short* hq2 = hs + (size_t)(mb + 2) * TT * HH + n0 + 2 * l15;
    unsigned short* hq3 = hs + (size_t)(mb + 3) * TT * HH + n0 + 2 * l15;

    // prologue: zero h buffer 0; load x for t=0
    for (int i = tid; i < G * HPAD / 2; i += 512)
        ((unsigned int*)hbl[0])[i] = 0u;
    float2 xv0 = *(const float2*)xq0;
    float2 xv1 = *(const float2*)xq1;
    float2 xv2 = *(const float2*)xq2;
    float2 xv3 = *(const float2*)xq3;
    __syncthreads();

    unsigned int sv0 = 0, sv1 = 0, sv2 = 0, sv3 = 0;

    for (int t = 0; t < TT; ++t) {
        const int p = t & 1;

        // A-fragments of current h (8 x ds_read_b128)
        const unsigned short* hrow = &hbl[p][l15][lg * 8];
        bf16x8 a0 = *(const bf16x8*)(hrow + 0 * 32);
        bf16x8 a1 = *(const bf16x8*)(hrow + 1 * 32);
        bf16x8 a2 = *(const bf16x8*)(hrow + 2 * 32);
        bf16x8 a3 = *(const bf16x8*)(hrow + 3 * 32);
        bf16x8 a4 = *(const bf16x8*)(hrow + 4 * 32);
        bf16x8 a5 = *(const bf16x8*)(hrow + 5 * 32);
        bf16x8 a6 = *(const bf16x8*)(hrow + 6 * 32);
        bf16x8 a7 = *(const bf16x8*)(hrow + 7 * 32);

        // deferred hs stores for t-1 (drain overlaps this whole step)
        if (t) {
            *(unsigned int*)hq0 = sv0; hq0 += HH;
            *(unsigned int*)hq1 = sv1; hq1 += HH;
            *(unsigned int*)hq2 = sv2; hq2 += HH;
            *(unsigned int*)hq3 = sv3; hq3 += HH;
        }

        // 16 MFMA: 2 chains of 8, C-in = x; setprio(1) favors this wave's
        // MFMA issue while the sibling wave on the SIMD is in its LDS phase
        f32x4v c0 = {xv0.x, xv1.x, xv2.x, xv3.x};
        f32x4v c1 = {xv0.y, xv1.y, xv2.y, xv3.y};
        __builtin_amdgcn_s_setprio(1);
        MM(a0, B00, c0) MM(a0, B10, c1)
        MM(a1, B01, c0) MM(a1, B11, c1)
        MM(a2, B02, c0) MM(a2, B12, c1)
        MM(a3, B03, c0) MM(a3, B13, c1)
        MM(a4, B04, c0) MM(a4, B14, c1)
        MM(a5, B05, c0) MM(a5, B15, c1)
        MM(a6, B06, c0) MM(a6, B16, c1)
        MM(a7, B07, c0) MM(a7, B17, c1)
        __builtin_amdgcn_s_setprio(0);

        // epilogue: tanh both chain outputs, pack, one b32 LDS write per row
#define EPI(r, sv) { \
        float h0 = tanh_fast(c0[r]); \
        float h1 = tanh_fast(c1[r]); \
        asm("v_cvt_pk_bf16_f32 %0, %1, %2" : "=v"(sv) : "v"(h0), "v"(h1)); \
        *(unsigned int*)&hbl[p ^ 1][lg * 4 + (r)][n0 + 2 * l15] = sv; }

        EPI(0, sv0)
        EPI(1, sv1)
        EPI(2, sv2)
        EPI(3, sv3)

        // prefetch x for t+1 (pointer bump; last-step read is in-bounds junk)
        xq0 += HH; xq1 += HH; xq2 += HH; xq3 += HH;
        xv0 = *(const float2*)xq0;
        xv1 = *(const float2*)xq1;
        xv2 = *(const float2*)xq2;
        xv3 = *(const float2*)xq3;

        __syncthreads();
    }

    // final stores (t = TT-1)
    *(unsigned int*)hq0 = sv0;
    *(unsigned int*)hq1 = sv1;
    *(unsigned int*)hq2 = sv2;
    *(unsigned int*)hq3 = sv3;
}

// ---------------------------------------------------------------------------
extern "C" void kernel_launch(void* const* d_in, const int* in_sizes, int n_in,
                              void* d_out, int out_size, void* d_ws, size_t ws_size,
                              hipStream_t stream)
{
    const float* x  = (const float*)d_in[0];   // [B,T,I]
    const float* Wi = (const float*)d_in[1];   // [H,I]
    const float* bi = (const float*)d_in[2];   // [H]
    const float* Wh = (const float*)d_in[3];   // [H,H]
    const float* bh = (const float*)d_in[4];   // [H]
    const float* Wo = (const float*)d_in[5];   // [O,H]
    const float* bo = (const float*)d_in[6];   // [O]
    float* out = (float*)d_out;                // [B,T,O] fp32

    const int M = BB * TT;                     // 131072 flattened rows

    // workspace: xproj fp32 [M,H] (134MB, permuted) | hs bf16 [M,H] (67MB, permuted)
    float* xproj = (float*)d_ws;
    unsigned short* hs = (unsigned short*)((char*)d_ws + (size_t)M * HH * sizeof(float));

    // Phase 1: xproj = x*Wi^T + (bi+bh), within-32 permuted columns (MFMA)
    gemm1_mfma<<<dim3(M / 128), 256, 0, stream>>>(x, Wi, bi, bh, xproj);

    // Phase 2: recurrence (4 CUs, 8 waves each, MFMA) — R8/R13 structure
    rnn_recurrence_mfma<<<dim3(4), 512, 0, stream>>>(xproj, Wh, hs);

    // Phase 3: out = hs*Wo^T + bo (MFMA, pos-space contraction)
    gemm3_mfma<<<dim3(M / 128), 256, 0, stream>>>(hs, Wo, bo, out);
}

// Round 15
// 1246.209 us; speedup vs baseline: 1.0890x; 1.0890x over previous
//
#include <hip/hip_runtime.h>
#include <hip/hip_bf16.h>

// Problem constants
#define BB 64
#define TT 2048
#define II 128
#define HH 256
#define OO 128

typedef float f32x4v __attribute__((ext_vector_type(4)));
typedef short bf16x8 __attribute__((ext_vector_type(8)));

__device__ __forceinline__ unsigned short f2bf(float f) {
    union { __hip_bfloat16 h; unsigned short u; } cv;
    cv.h = __float2bfloat16(f);   // RNE
    return cv.u;
}
__device__ __forceinline__ float tanh_fast(float x) {
    // tanh(x) = 1 - 2/(e^{2x}+1);  e^{2x} = 2^{x*2*log2(e)}
    float y = x * 2.88539008177793f;
    float e;
    asm("v_exp_f32 %0, %1" : "=v"(e) : "v"(y));
    return 1.0f - 2.0f * __builtin_amdgcn_rcpf(e + 1.0f);
}

// within-32 permutation: storage position p holds true column
//   T(p)   = (p & ~31) + 16*(p&1) + ((p&31)>>1)
//   pos(c) = (c & ~31) + 2*(c&15) + ((c&31)>>4)     (inverse; verified)

#define MM(a, b, c) c = __builtin_amdgcn_mfma_f32_16x16x32_bf16(a, b, c, 0, 0, 0);

// ---------------------------------------------------------------------------
// Phase 1 (MFMA): xproj[m][pos] = (x*Wi^T)[m][T(pos)] + bi + bh
// M-tile 128 (R14-verified). 256 thr / 4 waves; wave handles rows
// m0..m0+15 and m0+64..m0+79.
// ---------------------------------------------------------------------------
#define WIPAD 136   // ushorts per wiL row

__global__ __launch_bounds__(256) void gemm1_mfma(
    const float* __restrict__ x, const float* __restrict__ Wi,
    const float* __restrict__ bi, const float* __restrict__ bh,
    float* __restrict__ xproj)
{
    __shared__ __align__(16) unsigned short wiL[HH][WIPAD];   // 69.6 KB

    const int tid = threadIdx.x;
    const int wv = tid >> 6, lane = tid & 63;
    const int l15 = lane & 15, lg = lane >> 4;
    const int m0 = blockIdx.x * 128 + wv * 16;

    // stage Wi -> LDS bf16 (coalesced flat reads)
    for (int e = tid; e < HH * II; e += 256)
        wiL[e >> 7][e & 127] = f2bf(Wi[e]);
    __syncthreads();

    // A-frags: rows m0+l15 (a0..a3) and m0+64+l15 (a4..a7), fp32 -> bf16
    const float* xr0 = x + (size_t)(m0 + l15) * II + lg * 8;
    const float* xr1 = x + (size_t)(m0 + 64 + l15) * II + lg * 8;
    bf16x8 a0, a1, a2, a3, a4, a5, a6, a7;
#define LOADA1(ptr, q, dst) { \
        float4 u0 = *(const float4*)((ptr) + (q) * 32); \
        float4 u1 = *(const float4*)((ptr) + (q) * 32 + 4); \
        dst[0] = (short)f2bf(u0.x); dst[1] = (short)f2bf(u0.y); \
        dst[2] = (short)f2bf(u0.z); dst[3] = (short)f2bf(u0.w); \
        dst[4] = (short)f2bf(u1.x); dst[5] = (short)f2bf(u1.y); \
        dst[6] = (short)f2bf(u1.z); dst[7] = (short)f2bf(u1.w); }
    LOADA1(xr0, 0, a0) LOADA1(xr0, 1, a1) LOADA1(xr0, 2, a2) LOADA1(xr0, 3, a3)
    LOADA1(xr1, 0, a4) LOADA1(xr1, 1, a5) LOADA1(xr1, 2, a6) LOADA1(xr1, 3, a7)

    // 16 N-tiles x 4 K-steps x 2 M-subtiles; permuted scatter stores
#pragma unroll
    for (int nt = 0; nt < 16; ++nt) {
        const int c = nt * 16 + l15;            // true column
        const float bv = bi[c] + bh[c];
        f32x4v acc0 = {bv, bv, bv, bv};
        f32x4v acc1 = {bv, bv, bv, bv};
        const unsigned short* wrow = &wiL[nt * 16 + l15][lg * 8];
        bf16x8 b0 = *(const bf16x8*)(wrow + 0);
        bf16x8 b1 = *(const bf16x8*)(wrow + 32);
        bf16x8 b2 = *(const bf16x8*)(wrow + 64);
        bf16x8 b3 = *(const bf16x8*)(wrow + 96);
        MM(a0, b0, acc0) MM(a1, b1, acc0) MM(a2, b2, acc0) MM(a3, b3, acc0)
        MM(a4, b0, acc1) MM(a5, b1, acc1) MM(a6, b2, acc1) MM(a7, b3, acc1)

        const int pos = (c & ~31) + 2 * (c & 15) + ((c & 31) >> 4);
#pragma unroll
        for (int r = 0; r < 4; ++r) {
            xproj[(size_t)(m0 + lg * 4 + r) * HH + pos] = acc0[r];
            xproj[(size_t)(m0 + 64 + lg * 4 + r) * HH + pos] = acc1[r];
        }
    }
}

// ---------------------------------------------------------------------------
// Phase 3 (MFMA): out = hs*Wo^T + bo. hs bf16 pos-space; Wo staged to LDS
// pre-permuted. M-tile 128 (B-frag LDS reads amortized over 2 M-subtiles).
// ---------------------------------------------------------------------------
#define WOPAD 264   // ushorts per woL row

__global__ __launch_bounds__(256) void gemm3_mfma(
    const unsigned short* __restrict__ hs, const float* __restrict__ Wo,
    const float* __restrict__ bo, float* __restrict__ out)
{
    __shared__ __align__(16) unsigned short woL[OO][WOPAD];   // 67.6 KB

    const int tid = threadIdx.x;
    const int wv = tid >> 6, lane = tid & 63;
    const int l15 = lane & 15, lg = lane >> 4;
    const int m0 = blockIdx.x * 128 + wv * 16;

    // stage Wo -> LDS bf16, permuted into pos space
    for (int e = tid; e < OO * HH; e += 256) {
        const int o = e >> 8, c = e & 255;
        const int pos = (c & ~31) + 2 * (c & 15) + ((c & 31) >> 4);
        woL[o][pos] = f2bf(Wo[e]);
    }
    __syncthreads();

    // A-frags: rows m0+l15 and m0+64+l15 (pos-space), direct b128 global
    const unsigned short* hr0 = hs + (size_t)(m0 + l15) * HH + lg * 8;
    const unsigned short* hr1 = hs + (size_t)(m0 + 64 + l15) * HH + lg * 8;
    bf16x8 a0 = *(const bf16x8*)(hr0 + 0);
    bf16x8 a1 = *(const bf16x8*)(hr0 + 32);
    bf16x8 a2 = *(const bf16x8*)(hr0 + 64);
    bf16x8 a3 = *(const bf16x8*)(hr0 + 96);
    bf16x8 a4 = *(const bf16x8*)(hr0 + 128);
    bf16x8 a5 = *(const bf16x8*)(hr0 + 160);
    bf16x8 a6 = *(const bf16x8*)(hr0 + 192);
    bf16x8 a7 = *(const bf16x8*)(hr0 + 224);
    bf16x8 e0 = *(const bf16x8*)(hr1 + 0);
    bf16x8 e1 = *(const bf16x8*)(hr1 + 32);
    bf16x8 e2 = *(const bf16x8*)(hr1 + 64);
    bf16x8 e3 = *(const bf16x8*)(hr1 + 96);
    bf16x8 e4 = *(const bf16x8*)(hr1 + 128);
    bf16x8 e5 = *(const bf16x8*)(hr1 + 160);
    bf16x8 e6 = *(const bf16x8*)(hr1 + 192);
    bf16x8 e7 = *(const bf16x8*)(hr1 + 224);

    // 8 N-tiles x 8 K-steps x 2 M-subtiles
#pragma unroll
    for (int nt = 0; nt < 8; ++nt) {
        const float bv = bo[nt * 16 + l15];
        f32x4v acc0 = {bv, bv, bv, bv};
        f32x4v acc1 = {bv, bv, bv, bv};
        const unsigned short* wrow = &woL[nt * 16 + l15][lg * 8];
        bf16x8 b0 = *(const bf16x8*)(wrow + 0);
        bf16x8 b1 = *(const bf16x8*)(wrow + 32);
        bf16x8 b2 = *(const bf16x8*)(wrow + 64);
        bf16x8 b3 = *(const bf16x8*)(wrow + 96);
        bf16x8 b4 = *(const bf16x8*)(wrow + 128);
        bf16x8 b5 = *(const bf16x8*)(wrow + 160);
        bf16x8 b6 = *(const bf16x8*)(wrow + 192);
        bf16x8 b7 = *(const bf16x8*)(wrow + 224);
        MM(a0, b0, acc0) MM(a1, b1, acc0) MM(a2, b2, acc0) MM(a3, b3, acc0)
        MM(a4, b4, acc0) MM(a5, b5, acc0) MM(a6, b6, acc0) MM(a7, b7, acc0)
        MM(e0, b0, acc1) MM(e1, b1, acc1) MM(e2, b2, acc1) MM(e3, b3, acc1)
        MM(e4, b4, acc1) MM(e5, b5, acc1) MM(e6, b6, acc1) MM(e7, b7, acc1)

#pragma unroll
        for (int r = 0; r < 4; ++r) {
            out[(size_t)(m0 + lg * 4 + r) * OO + nt * 16 + l15] = acc0[r];
            out[(size_t)(m0 + 64 + lg * 4 + r) * OO + nt * 16 + l15] = acc1[r];
        }
    }
}

// ---------------------------------------------------------------------------
// Recurrence: R13 VERBATIM (best measured 1176 us; R14's setprio removed —
// it regressed 8% because barrier-locked waves gain nothing from priority).
// ---------------------------------------------------------------------------
#define G 16
#define HPAD 264    // ushorts per h row (528B)

__global__ __launch_bounds__(512) __attribute__((amdgpu_waves_per_eu(2, 2)))
void rnn_recurrence_mfma(
    const float* __restrict__ xproj, const float* __restrict__ Wh,
    unsigned short* __restrict__ hs)
{
    __shared__ __align__(16) unsigned short hbl[2][G][HPAD];

    const int blk  = blockIdx.x;         // 0..3
    const int tid  = threadIdx.x;        // 0..511
    const int wave = tid >> 6;           // 0..7
    const int lane = tid & 63;
    const int l15  = lane & 15;
    const int lg   = lane >> 4;          // 0..3
    const int n0   = wave * 32;          // wave's 32-unit block

    // one-time B-frags (within-32 K-gather)
#define LOADB(nt, kt, dst) { \
        const float* wp = Wh + (size_t)(n0 + (nt)*16 + l15) * HH + (kt)*32 + lg*4; \
        dst[0] = (short)f2bf(wp[0]);  dst[1] = (short)f2bf(wp[16]); \
        dst[2] = (short)f2bf(wp[1]);  dst[3] = (short)f2bf(wp[17]); \
        dst[4] = (short)f2bf(wp[2]);  dst[5] = (short)f2bf(wp[18]); \
        dst[6] = (short)f2bf(wp[3]);  dst[7] = (short)f2bf(wp[19]); }

    bf16x8 B00, B01, B02, B03, B04, B05, B06, B07;
    bf16x8 B10, B11, B12, B13, B14, B15, B16, B17;
    LOADB(0, 0, B00) LOADB(0, 1, B01) LOADB(0, 2, B02) LOADB(0, 3, B03)
    LOADB(0, 4, B04) LOADB(0, 5, B05) LOADB(0, 6, B06) LOADB(0, 7, B07)
    LOADB(1, 0, B10) LOADB(1, 1, B11) LOADB(1, 2, B12) LOADB(1, 3, B13)
    LOADB(1, 4, B14) LOADB(1, 5, B15) LOADB(1, 6, B16) LOADB(1, 7, B17)

    // per-thread 4 batch rows (m = lg*4 + r), permuted col offset n0 + 2*l15
    const int mb = blk * G + lg * 4;
    const float* xq0 = xproj + (size_t)(mb + 0) * TT * HH + n0 + 2 * l15;
    const float* xq1 = xproj + (size_t)(mb + 1) * TT * HH + n0 + 2 * l15;
    const float* xq2 = xproj + (size_t)(mb + 2) * TT * HH + n0 + 2 * l15;
    const float* xq3 = xproj + (size_t)(mb + 3) * TT * HH + n0 + 2 * l15;
    unsigned short* hq0 = hs + (size_t)(mb + 0) * TT * HH + n0 + 2 * l15;
    unsigned short* hq1 = hs + (size_t)(mb + 1) * TT * HH + n0 + 2 * l15;
    unsigned short* hq2 = hs + (size_t)(mb + 2) * TT * HH + n0 + 2 * l15;
    unsigned short* hq3 = hs + (size_t)(mb + 3) * TT * HH + n0 + 2 * l15;

    // prologue: zero h buffer 0; load x for t=0
    for (int i = tid; i < G * HPAD / 2; i += 512)
        ((unsigned int*)hbl[0])[i] = 0u;
    float2 xv0 = *(const float2*)xq0;
    float2 xv1 = *(const float2*)xq1;
    float2 xv2 = *(const float2*)xq2;
    float2 xv3 = *(const float2*)xq3;
    __syncthreads();

    unsigned int sv0 = 0, sv1 = 0, sv2 = 0, sv3 = 0;

    for (int t = 0; t < TT; ++t) {
        const int p = t & 1;

        // A-fragments of current h (8 x ds_read_b128)
        const unsigned short* hrow = &hbl[p][l15][lg * 8];
        bf16x8 a0 = *(const bf16x8*)(hrow + 0 * 32);
        bf16x8 a1 = *(const bf16x8*)(hrow + 1 * 32);
        bf16x8 a2 = *(const bf16x8*)(hrow + 2 * 32);
        bf16x8 a3 = *(const bf16x8*)(hrow + 3 * 32);
        bf16x8 a4 = *(const bf16x8*)(hrow + 4 * 32);
        bf16x8 a5 = *(const bf16x8*)(hrow + 5 * 32);
        bf16x8 a6 = *(const bf16x8*)(hrow + 6 * 32);
        bf16x8 a7 = *(const bf16x8*)(hrow + 7 * 32);

        // deferred hs stores for t-1 (drain overlaps this whole step)
        if (t) {
            *(unsigned int*)hq0 = sv0; hq0 += HH;
            *(unsigned int*)hq1 = sv1; hq1 += HH;
            *(unsigned int*)hq2 = sv2; hq2 += HH;
            *(unsigned int*)hq3 = sv3; hq3 += HH;
        }

        // 16 MFMA: 2 chains of 8, C-in = x (bias pre-folded in phase 1)
        f32x4v c0 = {xv0.x, xv1.x, xv2.x, xv3.x};
        f32x4v c1 = {xv0.y, xv1.y, xv2.y, xv3.y};
        MM(a0, B00, c0) MM(a0, B10, c1)
        MM(a1, B01, c0) MM(a1, B11, c1)
        MM(a2, B02, c0) MM(a2, B12, c1)
        MM(a3, B03, c0) MM(a3, B13, c1)
        MM(a4, B04, c0) MM(a4, B14, c1)
        MM(a5, B05, c0) MM(a5, B15, c1)
        MM(a6, B06, c0) MM(a6, B16, c1)
        MM(a7, B07, c0) MM(a7, B17, c1)

        // epilogue: tanh both chain outputs, pack, one b32 LDS write per row
#define EPI(r, sv) { \
        float h0 = tanh_fast(c0[r]); \
        float h1 = tanh_fast(c1[r]); \
        asm("v_cvt_pk_bf16_f32 %0, %1, %2" : "=v"(sv) : "v"(h0), "v"(h1)); \
        *(unsigned int*)&hbl[p ^ 1][lg * 4 + (r)][n0 + 2 * l15] = sv; }

        EPI(0, sv0)
        EPI(1, sv1)
        EPI(2, sv2)
        EPI(3, sv3)

        // prefetch x for t+1 (pointer bump; last-step read is in-bounds junk)
        xq0 += HH; xq1 += HH; xq2 += HH; xq3 += HH;
        xv0 = *(const float2*)xq0;
        xv1 = *(const float2*)xq1;
        xv2 = *(const float2*)xq2;
        xv3 = *(const float2*)xq3;

        __syncthreads();
    }

    // final stores (t = TT-1)
    *(unsigned int*)hq0 = sv0;
    *(unsigned int*)hq1 = sv1;
    *(unsigned int*)hq2 = sv2;
    *(unsigned int*)hq3 = sv3;
}

// ---------------------------------------------------------------------------
extern "C" void kernel_launch(void* const* d_in, const int* in_sizes, int n_in,
                              void* d_out, int out_size, void* d_ws, size_t ws_size,
                              hipStream_t stream)
{
    const float* x  = (const float*)d_in[0];   // [B,T,I]
    const float* Wi = (const float*)d_in[1];   // [H,I]
    const float* bi = (const float*)d_in[2];   // [H]
    const float* Wh = (const float*)d_in[3];   // [H,H]
    const float* bh = (const float*)d_in[4];   // [H]
    const float* Wo = (const float*)d_in[5];   // [O,H]
    const float* bo = (const float*)d_in[6];   // [O]
    float* out = (float*)d_out;                // [B,T,O] fp32

    const int M = BB * TT;                     // 131072 flattened rows

    // workspace: xproj fp32 [M,H] (134MB, permuted) | hs bf16 [M,H] (67MB, permuted)
    float* xproj = (float*)d_ws;
    unsigned short* hs = (unsigned short*)((char*)d_ws + (size_t)M * HH * sizeof(float));

    // Phase 1: xproj = x*Wi^T + (bi+bh), within-32 permuted columns (MFMA)
    gemm1_mfma<<<dim3(M / 128), 256, 0, stream>>>(x, Wi, bi, bh, xproj);

    // Phase 2: recurrence (4 CUs, 8 waves each, MFMA) — R8/R13 structure
    rnn_recurrence_mfma<<<dim3(4), 512, 0, stream>>>(xproj, Wh, hs);

    // Phase 3: out = hs*Wo^T + bo (MFMA, pos-space contraction)
    gemm3_mfma<<<dim3(M / 128), 256, 0, stream>>>(hs, Wo, bo, out);
}